// Round 2
// baseline (271.090 us; speedup 1.0000x reference)
//
#include <hip/hip_runtime.h>

// out[b,h,w,u] = ||x||^2 - 2 x.w + ||w||^2
// x: [524288, 64] fp32 (134 MB read once), w: [64,64] fp32 (16 KB, L2-hot),
// out: [524288, 64] fp32 (134 MB written once). Memory-bound, floor ~43 us.
//
// R1: latency-bound fix. Grid 1024->2048 blocks (8 blocks/CU -> 32 waves/CU,
// HW max; VGPR<=64 required for 8 waves/SIMD -- keep register count tight).
// Fold -w2/2 into MFMA acc init (epilogue = single fma per element).
// Non-temporal stores: Out is write-once, keep it out of L2/L3 so X stays
// L3-resident (FETCH_SIZE showed X is served half from L3).
//
// Per-wave tile: 16 rows x 64 units, mfma_f32_16x16x32_bf16.
//   A = w (units on M; 8 frags persistent in regs), B = x (rows on N, direct
//   global->reg dwordx4). C/D: col=lane&15 (row), row=quad*4+reg (unit) ->
//   each lane's 4 C-regs = 4 consecutive units -> dwordx4 stores.
// ||x||^2 / ||w||^2 in fp32 from originals; only cross term is bf16.

typedef float  float4v  __attribute__((ext_vector_type(4)));
typedef __bf16 bf16x8   __attribute__((ext_vector_type(8)));

static constexpr int kRows  = 16 * 128 * 256;  // 524288
static constexpr int kTiles = kRows / 16;      // 32768

__device__ __forceinline__ bf16x8 cvt2(float4v a, float4v b) {
  bf16x8 r;
  r[0] = (__bf16)a[0]; r[1] = (__bf16)a[1]; r[2] = (__bf16)a[2]; r[3] = (__bf16)a[3];
  r[4] = (__bf16)b[0]; r[5] = (__bf16)b[1]; r[6] = (__bf16)b[2]; r[7] = (__bf16)b[3];
  return r;
}

__global__ __launch_bounds__(256, 8) void sqdist_kernel(
    const float* __restrict__ X, const float* __restrict__ W,
    float* __restrict__ Out) {
  const int lane = threadIdx.x & 63;
  const int q    = lane >> 4;   // quad 0..3
  const int m    = lane & 15;

  // ---- Setup: w fragments (A operand) + acc-init = -||w_u||^2 / 2 ----
  // A layout: A[mdim = lane&15][k = q*8 + j]; frag kf covers k in [32*kf, +32).
  bf16x8  aw[4][2];
  float4v zinit[4];  // zinit[ut][r] = -0.5*||w_u||^2, u = 16*ut + q*4 + r
#pragma unroll
  for (int ut = 0; ut < 4; ++ut) {
    const float4v* wr = (const float4v*)(W + (ut * 16 + m) * 64);
    float4v v0 = wr[q * 2];
    float4v v1 = wr[q * 2 + 1];
    float4v v2 = wr[8 + q * 2];
    float4v v3 = wr[8 + q * 2 + 1];
    aw[ut][0] = cvt2(v0, v1);
    aw[ut][1] = cvt2(v2, v3);
    float s = 0.f;
#pragma unroll
    for (int i = 0; i < 4; ++i)
      s += v0[i] * v0[i] + v1[i] * v1[i] + v2[i] * v2[i] + v3[i] * v3[i];
    s += __shfl_xor(s, 16);   // reduce over quads -> lane holds ||w_(16*ut+m)||^2
    s += __shfl_xor(s, 32);
#pragma unroll
    for (int r = 0; r < 4; ++r)
      zinit[ut][r] = -0.5f * __shfl(s, q * 4 + r);  // unit this C-reg maps to
  }

  const int gw = blockIdx.x * (blockDim.x >> 6) + (threadIdx.x >> 6);
  const int nw = gridDim.x * (blockDim.x >> 6);

  for (int tile = gw; tile < kTiles; tile += nw) {
    // ---- Load this lane's slice of the 16-row x-tile (B operand) ----
    // B layout: B[k = q*8+j][n = lane&15]; lane reads row tile*16+m,
    // floats [q*8 .. +7] and [32+q*8 .. +7]. Every byte read exactly once.
    const float4v* xr = (const float4v*)(X + (tile * 16 + m) * 64);
    float4v x0 = xr[q * 2];
    float4v x1 = xr[q * 2 + 1];
    float4v x2 = xr[8 + q * 2];
    float4v x3 = xr[8 + q * 2 + 1];

    // ||x_row||^2 in fp32 (lane-partial over 16 elems, reduce over quads)
    float s = 0.f;
#pragma unroll
    for (int i = 0; i < 4; ++i)
      s += x0[i] * x0[i] + x1[i] * x1[i] + x2[i] * x2[i] + x3[i] * x3[i];
    s += __shfl_xor(s, 16);
    s += __shfl_xor(s, 32);   // C-col of this lane is m -> no further shfl

    bf16x8 bx0 = cvt2(x0, x1);
    bf16x8 bx1 = cvt2(x2, x3);

    // ---- 8 MFMAs: acc = -w2/2 + dot(w_u, x_row) ----
    float4v acc[4];
#pragma unroll
    for (int ut = 0; ut < 4; ++ut) {
      acc[ut] = __builtin_amdgcn_mfma_f32_16x16x32_bf16(aw[ut][0], bx0, zinit[ut], 0, 0, 0);
      acc[ut] = __builtin_amdgcn_mfma_f32_16x16x32_bf16(aw[ut][1], bx1, acc[ut], 0, 0, 0);
    }

    // ---- Epilogue: out = s - 2*acc ; 4x dwordx4 non-temporal stores ----
    float4v* orow = (float4v*)(Out + (tile * 16 + m) * 64);
#pragma unroll
    for (int ut = 0; ut < 4; ++ut) {
      float4v o;
#pragma unroll
      for (int r = 0; r < 4; ++r)
        o[r] = fmaf(-2.f, acc[ut][r], s);
      __builtin_nontemporal_store(o, &orow[ut * 4 + q]);  // floats [16*ut+4*q ..]
    }
  }
}

extern "C" void kernel_launch(void* const* d_in, const int* in_sizes, int n_in,
                              void* d_out, int out_size, void* d_ws, size_t ws_size,
                              hipStream_t stream) {
  const float* X = (const float*)d_in[0];
  const float* W = (const float*)d_in[1];
  float* Out = (float*)d_out;
  // 2048 blocks x 4 waves = 8192 waves = 32 waves/CU resident (HW max);
  // 32768 tiles -> 4 tiles/wave, grid-stride.
  sqdist_kernel<<<2048, 256, 0, stream>>>(X, W, Out);
}

// Round 3
// 270.809 us; speedup vs baseline: 1.0010x; 1.0010x over previous
//
#include <hip/hip_runtime.h>

// out[b,h,w,u] = ||x||^2 - 2 x.w + ||w||^2
// x: [524288, 64] fp32 (134 MB read once), w: [64,64] fp32 (16 KB, L2-hot),
// out: [524288, 64] fp32 (134 MB written once). Memory-bound, floor ~43 us.
//
// R2: REVERTED non-temporal stores (R1 post-mortem: wave's store instrs cover
// a 128B line only in aggregate across the 4 ut-stores; merge happens in L2,
// nt defeated it -> WRITE_SIZE 131->250 MB, FETCH 65->131 MB, dur 83->120 us).
// Keep: grid 2048 (8 blocks/CU -> 32 waves/CU; occupancy 30->60% was the real
// win of R1), launch_bounds(256,8), -w2/2 folded into MFMA acc init.
// No software pipeline: live-reg budget (aw32+zinit16+prefetch16+acc16) would
// spill under the 64-VGPR/8-wave cap.
//
// Per-wave tile: 16 rows x 64 units, mfma_f32_16x16x32_bf16.
//   A = w (units on M; 8 frags persistent in regs), B = x (rows on N, direct
//   global->reg dwordx4). C/D: col=lane&15 (row), row=quad*4+reg (unit) ->
//   each lane's 4 C-regs = 4 consecutive units -> dwordx4 stores.
// ||x||^2 / ||w||^2 in fp32 from originals; only cross term is bf16.

typedef float  float4v  __attribute__((ext_vector_type(4)));
typedef __bf16 bf16x8   __attribute__((ext_vector_type(8)));

static constexpr int kRows  = 16 * 128 * 256;  // 524288
static constexpr int kTiles = kRows / 16;      // 32768

__device__ __forceinline__ bf16x8 cvt2(float4v a, float4v b) {
  bf16x8 r;
  r[0] = (__bf16)a[0]; r[1] = (__bf16)a[1]; r[2] = (__bf16)a[2]; r[3] = (__bf16)a[3];
  r[4] = (__bf16)b[0]; r[5] = (__bf16)b[1]; r[6] = (__bf16)b[2]; r[7] = (__bf16)b[3];
  return r;
}

__global__ __launch_bounds__(256, 8) void sqdist_kernel(
    const float* __restrict__ X, const float* __restrict__ W,
    float* __restrict__ Out) {
  const int lane = threadIdx.x & 63;
  const int q    = lane >> 4;   // quad 0..3
  const int m    = lane & 15;

  // ---- Setup: w fragments (A operand) + acc-init = -||w_u||^2 / 2 ----
  // A layout: A[mdim = lane&15][k = q*8 + j]; frag kf covers k in [32*kf, +32).
  bf16x8  aw[4][2];
  float4v zinit[4];  // zinit[ut][r] = -0.5*||w_u||^2, u = 16*ut + q*4 + r
#pragma unroll
  for (int ut = 0; ut < 4; ++ut) {
    const float4v* wr = (const float4v*)(W + (ut * 16 + m) * 64);
    float4v v0 = wr[q * 2];
    float4v v1 = wr[q * 2 + 1];
    float4v v2 = wr[8 + q * 2];
    float4v v3 = wr[8 + q * 2 + 1];
    aw[ut][0] = cvt2(v0, v1);
    aw[ut][1] = cvt2(v2, v3);
    float s = 0.f;
#pragma unroll
    for (int i = 0; i < 4; ++i)
      s += v0[i] * v0[i] + v1[i] * v1[i] + v2[i] * v2[i] + v3[i] * v3[i];
    s += __shfl_xor(s, 16);   // reduce over quads -> lane holds ||w_(16*ut+m)||^2
    s += __shfl_xor(s, 32);
#pragma unroll
    for (int r = 0; r < 4; ++r)
      zinit[ut][r] = -0.5f * __shfl(s, q * 4 + r);  // unit this C-reg maps to
  }

  const int gw = blockIdx.x * (blockDim.x >> 6) + (threadIdx.x >> 6);
  const int nw = gridDim.x * (blockDim.x >> 6);

  for (int tile = gw; tile < kTiles; tile += nw) {
    // ---- Load this lane's slice of the 16-row x-tile (B operand) ----
    // B layout: B[k = q*8+j][n = lane&15]; lane reads row tile*16+m,
    // floats [q*8 .. +7] and [32+q*8 .. +7]. Every byte read exactly once.
    const float4v* xr = (const float4v*)(X + (tile * 16 + m) * 64);
    float4v x0 = xr[q * 2];
    float4v x1 = xr[q * 2 + 1];
    float4v x2 = xr[8 + q * 2];
    float4v x3 = xr[8 + q * 2 + 1];

    // ||x_row||^2 in fp32 (lane-partial over 16 elems, reduce over quads)
    float s = 0.f;
#pragma unroll
    for (int i = 0; i < 4; ++i)
      s += x0[i] * x0[i] + x1[i] * x1[i] + x2[i] * x2[i] + x3[i] * x3[i];
    s += __shfl_xor(s, 16);
    s += __shfl_xor(s, 32);   // C-col of this lane is m -> no further shfl

    bf16x8 bx0 = cvt2(x0, x1);
    bf16x8 bx1 = cvt2(x2, x3);

    // ---- 8 MFMAs: acc = -w2/2 + dot(w_u, x_row) ----
    float4v acc[4];
#pragma unroll
    for (int ut = 0; ut < 4; ++ut) {
      acc[ut] = __builtin_amdgcn_mfma_f32_16x16x32_bf16(aw[ut][0], bx0, zinit[ut], 0, 0, 0);
      acc[ut] = __builtin_amdgcn_mfma_f32_16x16x32_bf16(aw[ut][1], bx1, acc[ut], 0, 0, 0);
    }

    // ---- Epilogue: out = s - 2*acc ; 4x dwordx4 CACHED stores (merge in L2) ----
    float4v* orow = (float4v*)(Out + (tile * 16 + m) * 64);
#pragma unroll
    for (int ut = 0; ut < 4; ++ut) {
      float4v o;
#pragma unroll
      for (int r = 0; r < 4; ++r)
        o[r] = fmaf(-2.f, acc[ut][r], s);
      orow[ut * 4 + q] = o;   // floats [16*ut + 4*q .. +3] of this row
    }
  }
}

extern "C" void kernel_launch(void* const* d_in, const int* in_sizes, int n_in,
                              void* d_out, int out_size, void* d_ws, size_t ws_size,
                              hipStream_t stream) {
  const float* X = (const float*)d_in[0];
  const float* W = (const float*)d_in[1];
  float* Out = (float*)d_out;
  // 2048 blocks x 4 waves = 8192 waves = 32 waves/CU resident (HW max);
  // 32768 tiles -> 4 tiles/wave, grid-stride.
  sqdist_kernel<<<2048, 256, 0, stream>>>(X, W, Out);
}

// Round 4
// 270.429 us; speedup vs baseline: 1.0024x; 1.0014x over previous
//
#include <hip/hip_runtime.h>

// out[b,h,w,u] = ||x||^2 - 2 x.w + ||w||^2
// x: [524288, 64] fp32 (134 MB read once), w: [64,64] fp32 (16 KB, L2-hot),
// out: [524288, 64] fp32 (134 MB written once). Memory-bound, floor ~43 us.
//
// R3: LINE-ATOMIC STORES via LDS staging. R2 post-mortem: at 32 waves/CU the
// MFMA-layout stores (16 rows x 64 B chunks, 256 B stride per instruction;
// each 128 B line completed by TWO instructions) suffer partial-line eviction
// in the 4 MB/XCD L2 -> WRITE_SIZE 223 MB vs 134 ideal (+FETCH +14 MB RFO).
// At R0's 30% occupancy the merge window held (WRITE 131 MB); occupancy is
// what broke it, not the nt flag. Fix: stage the 4 KB out-tile in wave-private
// LDS (XOR swizzle, 8-phase bank floor), read back lane-linear, store 4x 1 KB
// contiguous bursts -- every store instruction fully covers 8 cachelines.
// LDS traffic 268 MB total @69 TB/s ~ 4 us aggregate: negligible.
//
// Per-wave tile: 16 rows x 64 units, mfma_f32_16x16x32_bf16.
//   A = w (units on M; 8 frags persistent), B = x (rows on N, direct
//   global->reg dwordx4). C/D: col=lane&15 (row), row=quad*4+reg (unit).
// ||x||^2 / ||w||^2 in fp32 from originals; only cross term is bf16.

typedef float  float4v  __attribute__((ext_vector_type(4)));
typedef __bf16 bf16x8   __attribute__((ext_vector_type(8)));

static constexpr int kRows  = 16 * 128 * 256;  // 524288
static constexpr int kTiles = kRows / 16;      // 32768

__device__ __forceinline__ bf16x8 cvt2(float4v a, float4v b) {
  bf16x8 r;
  r[0] = (__bf16)a[0]; r[1] = (__bf16)a[1]; r[2] = (__bf16)a[2]; r[3] = (__bf16)a[3];
  r[4] = (__bf16)b[0]; r[5] = (__bf16)b[1]; r[6] = (__bf16)b[2]; r[7] = (__bf16)b[3];
  return r;
}

__global__ __launch_bounds__(256, 8) void sqdist_kernel(
    const float* __restrict__ X, const float* __restrict__ W,
    float* __restrict__ Out) {
  // 4 KB staging region per wave (16 rows x 16 float4-columns), XOR-swizzled.
  __shared__ float4v stage[4][256];
  const int widx = threadIdx.x >> 6;
  const int lane = threadIdx.x & 63;
  const int q    = lane >> 4;   // quad 0..3
  const int m    = lane & 15;
  float4v* wbuf = stage[widx];

  // ---- Setup: w fragments (A operand) + acc-init = -||w_u||^2 / 2 ----
  bf16x8  aw[4][2];
  float4v zinit[4];  // zinit[ut][r] = -0.5*||w_u||^2, u = 16*ut + q*4 + r
#pragma unroll
  for (int ut = 0; ut < 4; ++ut) {
    const float4v* wr = (const float4v*)(W + (ut * 16 + m) * 64);
    float4v v0 = wr[q * 2];
    float4v v1 = wr[q * 2 + 1];
    float4v v2 = wr[8 + q * 2];
    float4v v3 = wr[8 + q * 2 + 1];
    aw[ut][0] = cvt2(v0, v1);
    aw[ut][1] = cvt2(v2, v3);
    float s = 0.f;
#pragma unroll
    for (int i = 0; i < 4; ++i)
      s += v0[i] * v0[i] + v1[i] * v1[i] + v2[i] * v2[i] + v3[i] * v3[i];
    s += __shfl_xor(s, 16);
    s += __shfl_xor(s, 32);
#pragma unroll
    for (int r = 0; r < 4; ++r)
      zinit[ut][r] = -0.5f * __shfl(s, q * 4 + r);
  }

  const int gw = blockIdx.x * (blockDim.x >> 6) + (threadIdx.x >> 6);
  const int nw = gridDim.x * (blockDim.x >> 6);

  for (int tile = gw; tile < kTiles; tile += nw) {
    // ---- Load x B-frags direct global->reg (lane: row tile*16+m) ----
    const float4v* xr = (const float4v*)(X + (tile * 16 + m) * 64);
    float4v x0 = xr[q * 2];
    float4v x1 = xr[q * 2 + 1];
    float4v x2 = xr[8 + q * 2];
    float4v x3 = xr[8 + q * 2 + 1];

    float s = 0.f;
#pragma unroll
    for (int i = 0; i < 4; ++i)
      s += x0[i] * x0[i] + x1[i] * x1[i] + x2[i] * x2[i] + x3[i] * x3[i];
    s += __shfl_xor(s, 16);
    s += __shfl_xor(s, 32);   // ||x_(tile*16+m)||^2 ; this lane's C-col is m

    bf16x8 bx0 = cvt2(x0, x1);
    bf16x8 bx1 = cvt2(x2, x3);

    // ---- 8 MFMAs: acc = -w2/2 + dot(w_u, x_row) ----
    float4v acc[4];
#pragma unroll
    for (int ut = 0; ut < 4; ++ut) {
      acc[ut] = __builtin_amdgcn_mfma_f32_16x16x32_bf16(aw[ut][0], bx0, zinit[ut], 0, 0, 0);
      acc[ut] = __builtin_amdgcn_mfma_f32_16x16x32_bf16(aw[ut][1], bx1, acc[ut], 0, 0, 0);
    }

    // ---- Stage out-tile to LDS (C layout -> row-major, XOR swizzle) ----
    // Value (row m, float4-col 4*ut+q) -> slot m*16 + ((4ut+q)^m).
#pragma unroll
    for (int ut = 0; ut < 4; ++ut) {
      float4v o;
#pragma unroll
      for (int r = 0; r < 4; ++r)
        o[r] = fmaf(-2.f, acc[ut][r], s);
      wbuf[m * 16 + (((ut << 2) | q) ^ m)] = o;
    }
    // Wave-private region: DS pipe is in-order per wave; compiler inserts
    // lgkmcnt waits for the write->read dependency. No barrier needed.

    // ---- Read back lane-linear, store 4x 1 KB line-atomic bursts ----
    float4v* obase = (float4v*)(Out + tile * 16 * 64);  // tile base, float4 units
#pragma unroll
    for (int i = 0; i < 4; ++i) {
      const int r = i * 4 + q;                 // row within tile this lane emits
      float4v t = wbuf[r * 16 + (m ^ r)];      // (row r, col m) unswizzled
      obase[i * 64 + lane] = t;                // bytes tile*4096 + i*1024 + lane*16
    }
  }
}

extern "C" void kernel_launch(void* const* d_in, const int* in_sizes, int n_in,
                              void* d_out, int out_size, void* d_ws, size_t ws_size,
                              hipStream_t stream) {
  const float* X = (const float*)d_in[0];
  const float* W = (const float*)d_in[1];
  float* Out = (float*)d_out;
  // 2048 blocks x 4 waves = 32 waves/CU resident; 32768 tiles -> 4 tiles/wave.
  sqdist_kernel<<<2048, 256, 0, stream>>>(X, W, Out);
}